// Round 4
// baseline (472.257 us; speedup 1.0000x reference)
//
#include <hip/hip_runtime.h>
#include <hip/hip_bf16.h>
#include <stdint.h>

#define BB 16
#define TT 1024
#define DD 256
#define NACC 64   // spread accumulator slots

typedef __attribute__((ext_vector_type(8))) short short8;
typedef __attribute__((ext_vector_type(4))) float floatx4;
typedef __attribute__((ext_vector_type(4))) float fvec4;

__device__ __forceinline__ unsigned short f2bf(float f) {
    union { float f; unsigned int u; } c; c.f = f;
    unsigned int u = c.u;
    unsigned int r = (u + 0x7FFFu + ((u >> 16) & 1u)) >> 16;
    return (unsigned short)r;
}

// One 64-lane wave per row of z. Also zeroes acc slots + done-counter.
__global__ __launch_bounds__(256) void prep_kernel(
    const float* __restrict__ z, float* __restrict__ z2,
    unsigned short* __restrict__ zb, double* __restrict__ acc,
    unsigned int* __restrict__ cnt) {
    if (blockIdx.x == 0) {
        if (threadIdx.x < NACC) acc[threadIdx.x] = 0.0;
        if (threadIdx.x == NACC) *cnt = 0u;
    }
    const int lane = threadIdx.x & 63;
    const int row  = blockIdx.x * 4 + (threadIdx.x >> 6);   // [0, BB*TT)
    const float4 v = ((const float4*)(z + (size_t)row * DD))[lane];
    float ss = v.x * v.x + v.y * v.y + v.z * v.z + v.w * v.w;
    ushort4 o;
    o.x = f2bf(v.x); o.y = f2bf(v.y); o.z = f2bf(v.z); o.w = f2bf(v.w);
    ((ushort4*)(zb + (size_t)row * DD))[lane] = o;
#pragma unroll
    for (int off = 32; off > 0; off >>= 1) ss += __shfl_down(ss, off);
    if (lane == 0) z2[row] = ss;
}

// One wave = TWO s-adjacent 32x32 tiles (t0, s0) and (t0, s0+32).
// gt loads for the next chunk are issued while the previous chunk's epilogue
// runs, keeping the HBM stream continuous. A-frags + z2t reused across both.
// A-frag: lane holds z[t0 + (lane&15)][k*32 + (lane>>4)*8 .. +7]
// C/D:    G[t0 + (lane>>4)*4 + r][s0 + (lane&15)]   [m89/m91 layout]
__global__ __launch_bounds__(256) void patch_kernel(
    const unsigned short* __restrict__ zb, const float* __restrict__ z2,
    const float* __restrict__ gt, const float* __restrict__ sigma,
    double* __restrict__ acc, unsigned int* __restrict__ cnt,
    float* __restrict__ out) {
    const float LOG2E = 1.4426950408889634f;
    const float s0v = sigma[0], s1v = sigma[1], s2v = sigma[2], s3v = sigma[3];
    const float nc0 = -LOG2E * 0.5f / (s0v * s0v);
    const float nc1 = -LOG2E * 0.5f / (s1v * s1v);
    const float nc2 = -LOG2E * 0.5f / (s2v * s2v);
    const float nc3 = -LOG2E * 0.5f / (s3v * s3v);

    const int tid  = threadIdx.x;
    const int lane = tid & 63;
    const int quad = lane >> 4;
    const int m    = lane & 15;
    const int wid  = blockIdx.x * 4 + (tid >> 6);   // [0, 8192): one s-pair

    const int b   = wid >> 9;
    const int rem = wid & 511;
    const int t0  = (rem >> 4) << 5;   // 32 t-tiles
    const int s0  = (rem & 15) << 6;   // 16 s-pairs, 64 wide

    const float* gtb = gt + (size_t)b * TT * TT * 4;
    const int    tq  = t0 + quad * 4;

    // ---- gt tileA half1 (rows rr=0,1; cols s0..s0+31): 8 nontemporal f4 ----
    fvec4 gtv[8];
#define GT_LOAD(dst, colbase)                                                   \
    {                                                                           \
        _Pragma("unroll")                                                       \
        for (int r = 0; r < 2; ++r) {                                           \
            const size_t row0 = (size_t)(tq + rrbase + r) * TT;                 \
            const size_t row1 = (size_t)(tq + 16 + rrbase + r) * TT;            \
            dst[r * 4 + 0] = __builtin_nontemporal_load((const fvec4*)(gtb + (row0 + (colbase) + m) * 4));        \
            dst[r * 4 + 1] = __builtin_nontemporal_load((const fvec4*)(gtb + (row0 + (colbase) + 16 + m) * 4));   \
            dst[r * 4 + 2] = __builtin_nontemporal_load((const fvec4*)(gtb + (row1 + (colbase) + m) * 4));        \
            dst[r * 4 + 3] = __builtin_nontemporal_load((const fvec4*)(gtb + (row1 + (colbase) + 16 + m) * 4));   \
        }                                                                       \
    }
    {
        const int rrbase = 0;
        GT_LOAD(gtv, s0)
    }

    // ---- both Gram tiles in one k-loop (A-frags loaded once) ----
    const unsigned short* zrow = zb + (size_t)b * TT * DD;
    const short8* at0  = (const short8*)(zrow + (t0 + m) * DD + quad * 8);
    const short8* at1  = (const short8*)(zrow + (t0 + 16 + m) * DD + quad * 8);
    const short8* bsA0 = (const short8*)(zrow + (s0 + m) * DD + quad * 8);
    const short8* bsA1 = (const short8*)(zrow + (s0 + 16 + m) * DD + quad * 8);
    const short8* bsB0 = (const short8*)(zrow + (s0 + 32 + m) * DD + quad * 8);
    const short8* bsB1 = (const short8*)(zrow + (s0 + 48 + m) * DD + quad * 8);

    floatx4 gA00 = {0.f,0.f,0.f,0.f}, gA01 = {0.f,0.f,0.f,0.f};
    floatx4 gA10 = {0.f,0.f,0.f,0.f}, gA11 = {0.f,0.f,0.f,0.f};
    floatx4 gB00 = {0.f,0.f,0.f,0.f}, gB01 = {0.f,0.f,0.f,0.f};
    floatx4 gB10 = {0.f,0.f,0.f,0.f}, gB11 = {0.f,0.f,0.f,0.f};
#pragma unroll
    for (int k = 0; k < 8; ++k) {
        const short8 a0 = at0[k * 4];
        const short8 a1 = at1[k * 4];
        const short8 b0 = bsA0[k * 4];
        const short8 b1 = bsA1[k * 4];
        const short8 b2 = bsB0[k * 4];
        const short8 b3 = bsB1[k * 4];
        gA00 = __builtin_amdgcn_mfma_f32_16x16x32_bf16(a0, b0, gA00, 0, 0, 0);
        gA01 = __builtin_amdgcn_mfma_f32_16x16x32_bf16(a0, b1, gA01, 0, 0, 0);
        gA10 = __builtin_amdgcn_mfma_f32_16x16x32_bf16(a1, b0, gA10, 0, 0, 0);
        gA11 = __builtin_amdgcn_mfma_f32_16x16x32_bf16(a1, b1, gA11, 0, 0, 0);
        gB00 = __builtin_amdgcn_mfma_f32_16x16x32_bf16(a0, b2, gB00, 0, 0, 0);
        gB01 = __builtin_amdgcn_mfma_f32_16x16x32_bf16(a0, b3, gB01, 0, 0, 0);
        gB10 = __builtin_amdgcn_mfma_f32_16x16x32_bf16(a1, b2, gB10, 0, 0, 0);
        gB11 = __builtin_amdgcn_mfma_f32_16x16x32_bf16(a1, b3, gB11, 0, 0, 0);
    }

    const float* z2b   = z2 + b * TT;
    const float  z2sA0 = z2b[s0 + m];
    const float  z2sA1 = z2b[s0 + 16 + m];
    const float  z2sB0 = z2b[s0 + 32 + m];
    const float  z2sB1 = z2b[s0 + 48 + m];

    float partial = 0.f;
    fvec4 gtn[8];   // next-chunk prefetch buffer

#define EPILOGUE(src, rrbase, G00, G01, G10, G11, Z2S0, Z2S1)                   \
    {                                                                           \
        _Pragma("unroll")                                                       \
        for (int r = 0; r < 2; ++r) {                                           \
            const int rr = rrbase + r;                                          \
            const float z2t0 = z2b[tq + rr];                                    \
            const float z2t1 = z2b[tq + 16 + rr];                               \
            const float e00 = z2t0 + Z2S0, e01 = z2t0 + Z2S1;                   \
            const float e10 = z2t1 + Z2S0, e11 = z2t1 + Z2S1;                   \
            fvec4 d;                                                            \
            d = src[r * 4 + 0];                                                 \
            partial = fmaf(exp2f(fmaf(nc3, d.w * d.w, fmaf(nc2, d.z * d.z,      \
                      fmaf(nc1, d.y * d.y, nc0 * d.x * d.x)))),                 \
                      fmaf(-2.f, G00[rr], e00), partial);                       \
            d = src[r * 4 + 1];                                                 \
            partial = fmaf(exp2f(fmaf(nc3, d.w * d.w, fmaf(nc2, d.z * d.z,      \
                      fmaf(nc1, d.y * d.y, nc0 * d.x * d.x)))),                 \
                      fmaf(-2.f, G01[rr], e01), partial);                       \
            d = src[r * 4 + 2];                                                 \
            partial = fmaf(exp2f(fmaf(nc3, d.w * d.w, fmaf(nc2, d.z * d.z,      \
                      fmaf(nc1, d.y * d.y, nc0 * d.x * d.x)))),                 \
                      fmaf(-2.f, G10[rr], e10), partial);                       \
            d = src[r * 4 + 3];                                                 \
            partial = fmaf(exp2f(fmaf(nc3, d.w * d.w, fmaf(nc2, d.z * d.z,      \
                      fmaf(nc1, d.y * d.y, nc0 * d.x * d.x)))),                 \
                      fmaf(-2.f, G11[rr], e11), partial);                       \
        }                                                                       \
    }

    { const int rrbase = 2; GT_LOAD(gtn, s0) }        // tileA half2 in flight
    EPILOGUE(gtv, 0, gA00, gA01, gA10, gA11, z2sA0, z2sA1)
    { const int rrbase = 0; GT_LOAD(gtv, s0 + 32) }   // tileB half1 in flight
    EPILOGUE(gtn, 2, gA00, gA01, gA10, gA11, z2sA0, z2sA1)
    { const int rrbase = 2; GT_LOAD(gtn, s0 + 32) }   // tileB half2 in flight
    EPILOGUE(gtv, 0, gB00, gB01, gB10, gB11, z2sB0, z2sB1)
    EPILOGUE(gtn, 2, gB00, gB01, gB10, gB11, z2sB0, z2sB1)

    // wave reduce -> block reduce -> one f64 atomic per block (spread slots)
#pragma unroll
    for (int off = 32; off > 0; off >>= 1) partial += __shfl_down(partial, off);
    __shared__ float red[4];
    __shared__ int is_last;
    if (lane == 0) red[tid >> 6] = partial;
    __syncthreads();
    if (tid == 0) {
        atomicAdd(&acc[blockIdx.x & (NACC - 1)],
                  (double)(red[0] + red[1] + red[2] + red[3]));
        __threadfence();
        const unsigned int done = atomicAdd(cnt, 1u);
        is_last = (done == gridDim.x - 1) ? 1 : 0;
    }
    __syncthreads();
    // last block finalizes: atomic-read the 64 slots, wave-reduce, write out
    if (is_last && tid < NACC) {
        double v = atomicAdd(&acc[tid], 0.0);
#pragma unroll
        for (int off = 32; off > 0; off >>= 1) v += __shfl_down(v, off);
        if (tid == 0)
            out[0] = (float)(v * (1.0 / ((double)BB * (double)TT * (double)TT)));
    }
}

extern "C" void kernel_launch(void* const* d_in, const int* in_sizes, int n_in,
                              void* d_out, int out_size, void* d_ws, size_t ws_size,
                              hipStream_t stream) {
    const float* z     = (const float*)d_in[0];   // [16,1024,256]
    const float* gt    = (const float*)d_in[1];   // [16,1024,1024,4]
    const float* sigma = (const float*)d_in[2];   // [4]
    float* out = (float*)d_out;

    // ws: [0,512)=64 f64 acc | 512: u32 done-counter | 1024: z2 (64 KB) | then zb (8 MB)
    char* ws = (char*)d_ws;
    double* acc        = (double*)ws;
    unsigned int* cnt  = (unsigned int*)(ws + 512);
    float* z2          = (float*)(ws + 1024);
    unsigned short* zb = (unsigned short*)(ws + 1024 + (size_t)BB * TT * sizeof(float));

    prep_kernel<<<BB * TT / 4, 256, 0, stream>>>(z, z2, zb, acc, cnt);
    patch_kernel<<<BB * (TT / 32) * (TT / 64) / 4, 256, 0, stream>>>(zb, z2, gt, sigma, acc, cnt, out);
}